// Round 7
// baseline (511.529 us; speedup 1.0000x reference)
//
#include <hip/hip_runtime.h>
#include <math.h>

#define BIGF 3.0e38f

// ===========================================================================
// Spatial-hash KNN (K=3).
// Selection must replicate the np reference's fp32 expansion distance:
//   sx  = (x*x + y*y) + z*z            (sequential, individually rounded)
//   dot = (p0 + p1) + p2, p_k = q_k*s_k
//   d2  = (sy + sx) - 2*dot
// evaluated with fp contract(off) — hipcc's default -ffp-contract=fast
// selects different neighbors (verified rounds 3-6). DO NOT TOUCH.
// Tie-break: lexicographic (d, idx) == stable top_k smallest-index-first.
// ===========================================================================

__device__ __forceinline__ int cell_clamp(float v, int G) {
  int c = (int)(v * (float)G);
  return min(G - 1, max(0, c));
}

// ---- count: 3 point sets in one dispatch (blocks 0-63 / 64-79 / 80-95) ----
__global__ __launch_bounds__(256) void cell_count3_kernel(
    const float* __restrict__ p1, int n1, int g1, int* __restrict__ c1,
    const float* __restrict__ p2, int n2, int g2, int* __restrict__ c2,
    const float* __restrict__ p3, int n3, int g3, int* __restrict__ c3)
{
  int b = blockIdx.x;
  const float* p; int n, G; int* cnt; int i;
  if (b < 64)      { p = p1; n = n1; G = g1; cnt = c1; i = b * 256 + threadIdx.x; }
  else if (b < 80) { p = p2; n = n2; G = g2; cnt = c2; i = (b - 64) * 256 + threadIdx.x; }
  else             { p = p3; n = n3; G = g3; cnt = c3; i = (b - 80) * 256 + threadIdx.x; }
  if (i >= n) return;
  int cx = cell_clamp(p[3 * i],     G);
  int cy = cell_clamp(p[3 * i + 1], G);
  int cz = cell_clamp(p[3 * i + 2], G);
  atomicAdd(&cnt[(cz * G + cy) * G + cx], 1);
}

// ---- exclusive prefix over 3 grids (block 0: M=4096, blocks 1,2: M=512) ---
__global__ __launch_bounds__(256) void prefix3_kernel(
    const int* __restrict__ c1, int* __restrict__ o1, int* __restrict__ u1,
    const int* __restrict__ c2, int* __restrict__ o2, int* __restrict__ u2,
    const int* __restrict__ c3, int* __restrict__ o3, int* __restrict__ u3)
{
  const int* cnt; int* offs; int* cur; int M;
  if (blockIdx.x == 0)      { cnt = c1; offs = o1; cur = u1; M = 4096; }
  else if (blockIdx.x == 1) { cnt = c2; offs = o2; cur = u2; M = 512; }
  else                      { cnt = c3; offs = o3; cur = u3; M = 512; }
  __shared__ int ps[256];
  const int tid = threadIdx.x;
  const int per = M >> 8;          // 16 or 2
  const int base = tid * per;
  int s = 0;
  for (int j = 0; j < per; ++j) s += cnt[base + j];
  ps[tid] = s;
  __syncthreads();
  for (int off = 1; off < 256; off <<= 1) {
    int v = (tid >= off) ? ps[tid - off] : 0;
    __syncthreads();
    ps[tid] += v;
    __syncthreads();
  }
  int run = (tid > 0) ? ps[tid - 1] : 0;
  for (int j = 0; j < per; ++j) {
    offs[base + j] = run; cur[base + j] = run;
    run += cnt[base + j];
  }
  if (tid == 255) offs[M] = run;
}

// ---- scatter: sorted float4(x,y,z,sx) + original index -------------------
__global__ __launch_bounds__(256) void scatter3_kernel(
    const float* __restrict__ p1, int n1, int g1, int* __restrict__ u1, float4* __restrict__ s1, int* __restrict__ x1,
    const float* __restrict__ p2, int n2, int g2, int* __restrict__ u2, float4* __restrict__ s2, int* __restrict__ x2,
    const float* __restrict__ p3, int n3, int g3, int* __restrict__ u3, float4* __restrict__ s3, int* __restrict__ x3)
{
  #pragma clang fp contract(off)
  int b = blockIdx.x;
  const float* p; int n, G; int* cur; float4* spts; int* sidx; int i;
  if (b < 64)      { p = p1; n = n1; G = g1; cur = u1; spts = s1; sidx = x1; i = b * 256 + threadIdx.x; }
  else if (b < 80) { p = p2; n = n2; G = g2; cur = u2; spts = s2; sidx = x2; i = (b - 64) * 256 + threadIdx.x; }
  else             { p = p3; n = n3; G = g3; cur = u3; spts = s3; sidx = x3; i = (b - 80) * 256 + threadIdx.x; }
  if (i >= n) return;
  float x = p[3 * i], y = p[3 * i + 1], z = p[3 * i + 2];
  int cx = cell_clamp(x, G), cy = cell_clamp(y, G), cz = cell_clamp(z, G);
  int c = (cz * G + cy) * G + cx;
  int pos = atomicAdd(&cur[c], 1);
  float sx = (x * x + y * y) + z * z;   // sequential, no contraction
  spts[pos] = make_float4(x, y, z, sx);
  sidx[pos] = i;
}

// ---- query: expanding-shell 3-NN + fused weight/output -------------------
// mode 0: write w[Nq,3], idx[Nq,3]
// mode 1: out3 = base3 - sum_k w_k * feat3[idx_k]
// mode 2: out3 =         sum_k w_k * feat3[idx_k]
#define VISIT_CELL(XX)                                                        \
  { int xx_ = (XX);                                                           \
    if (xx_ >= 0 && xx_ < G) {                                                \
      int c_ = (z_ * G + y_) * G + xx_;                                       \
      int js = offs[c_], je = offs[c_ + 1];                                   \
      for (int j = js; j < je; ++j) {                                         \
        float4 s = spts[j];                                                   \
        float p0 = qx * s.x, p1 = qy * s.y, p2 = qz * s.z;                    \
        float dt = (p0 + p1) + p2;                                            \
        float S  = sy + s.w;                                                  \
        float dd = S - 2.0f * dt;                                             \
        int   id = sidx[j];                                                   \
        bool l0 = (dd < d0) || (dd == d0 && id < i0);                         \
        bool l1 = (dd < d1) || (dd == d1 && id < i1);                         \
        bool l2 = (dd < d2v) || (dd == d2v && id < i2);                       \
        float nd0 = l0 ? dd : d0; int ni0 = l0 ? id : i0;                     \
        float nd1 = l0 ? d0 : (l1 ? dd : d1);                                 \
        int   ni1 = l0 ? i0 : (l1 ? id : i1);                                 \
        float nd2 = l1 ? d1 : (l2 ? dd : d2v);                                \
        int   ni2 = l1 ? i1 : (l2 ? id : i2);                                 \
        d0 = nd0; d1 = nd1; d2v = nd2; i0 = ni0; i1 = ni1; i2 = ni2;          \
      } } }

__global__ __launch_bounds__(64) void knn_grid_kernel(
    const float* __restrict__ qpos, int Nq, int G,
    const int* __restrict__ offs,
    const float4* __restrict__ spts,
    const int* __restrict__ sidx,
    int mode,
    const float* __restrict__ base3,
    const float* __restrict__ feat3,
    float* __restrict__ w_out, int* __restrict__ i_out,
    float* __restrict__ out3)
{
  #pragma clang fp contract(off)
  const int q = blockIdx.x * 64 + threadIdx.x;
  if (q >= Nq) return;
  const float qx = qpos[3 * q], qy = qpos[3 * q + 1], qz = qpos[3 * q + 2];
  const float sy = (qx * qx + qy * qy) + qz * qz;  // sequential, no contraction
  const float cs = 1.0f / (float)G;
  const int cx = cell_clamp(qx, G), cy = cell_clamp(qy, G), cz = cell_clamp(qz, G);

  float d0 = BIGF, d1 = BIGF, d2v = BIGF;
  int i0 = -1, i1 = -1, i2 = -1;

  for (int r = 0; r < G; ++r) {
    if (r >= 2) {
      // cells at chebyshev >= r have true d >= (r-1)*cs; expansion-d differs
      // from true-d by <= ~1.2e-7, margin 1e-6 keeps the bound conservative.
      float b = (float)(r - 1) * cs;
      if (d2v <= b * b - 1e-6f) break;
    }
    for (int dz = -r; dz <= r; ++dz) {
      int z_ = cz + dz;
      if (z_ < 0 || z_ >= G) continue;
      int adz = dz < 0 ? -dz : dz;
      for (int dy = -r; dy <= r; ++dy) {
        int y_ = cy + dy;
        if (y_ < 0 || y_ >= G) continue;
        int ady = dy < 0 ? -dy : dy;
        bool edge = (adz == r) || (ady == r);
        if (edge) {
          for (int dx = -r; dx <= r; ++dx) VISIT_CELL(cx + dx)
        } else {
          VISIT_CELL(cx - r)
          VISIT_CELL(cx + r)
        }
      }
    }
  }

  float w0 = 1.0f / fmaxf(d0, 1e-16f);
  float w1 = 1.0f / fmaxf(d1, 1e-16f);
  float w2 = 1.0f / fmaxf(d2v, 1e-16f);
  float inv = 1.0f / (w0 + w1 + w2);
  w0 *= inv; w1 *= inv; w2 *= inv;

  if (mode == 0) {
    w_out[(size_t)q * 3 + 0] = w0; w_out[(size_t)q * 3 + 1] = w1; w_out[(size_t)q * 3 + 2] = w2;
    i_out[(size_t)q * 3 + 0] = i0; i_out[(size_t)q * 3 + 1] = i1; i_out[(size_t)q * 3 + 2] = i2;
  } else {
    #pragma unroll
    for (int f = 0; f < 3; ++f) {
      float v = w0 * feat3[(size_t)i0 * 3 + f]
              + w1 * feat3[(size_t)i1 * 3 + f]
              + w2 * feat3[(size_t)i2 * 3 + f];
      out3[(size_t)q * 3 + f] = (mode == 1) ? (base3[(size_t)q * 3 + f] - v) : v;
    }
  }
}

// ---------------------------------------------------------------------------
// t[q, :] = emb1[q, :] - sum_k w_k * emb2[idx_k, :]     (F = 256, float4)
// ---------------------------------------------------------------------------
__global__ __launch_bounds__(256) void build_t_kernel(
    const float* __restrict__ emb1, const float* __restrict__ emb2,
    const float* __restrict__ w, const int* __restrict__ idx,
    float* __restrict__ t, int Nq)
{
  int gid = blockIdx.x * 256 + threadIdx.x;
  int q = gid >> 6, c4 = gid & 63;
  if (q >= Nq) return;
  float w0 = w[(size_t)q * 3 + 0], w1 = w[(size_t)q * 3 + 1], w2 = w[(size_t)q * 3 + 2];
  int i0 = idx[(size_t)q * 3 + 0], i1 = idx[(size_t)q * 3 + 1], i2 = idx[(size_t)q * 3 + 2];
  const float4* e1 = (const float4*)emb1;
  const float4* e2 = (const float4*)emb2;
  float4 a  = e1[(size_t)q * 64 + c4];
  float4 f0 = e2[(size_t)i0 * 64 + c4];
  float4 f1 = e2[(size_t)i1 * 64 + c4];
  float4 f2 = e2[(size_t)i2 * 64 + c4];
  float4 r;
  r.x = a.x - (w0 * f0.x + w1 * f1.x + w2 * f2.x);
  r.y = a.y - (w0 * f0.y + w1 * f1.y + w2 * f2.y);
  r.z = a.z - (w0 * f0.z + w1 * f1.z + w2 * f2.z);
  r.w = a.w - (w0 * f0.w + w1 * f1.w + w2 * f2.w);
  ((float4*)t)[(size_t)q * 64 + c4] = r;
}

// ---------------------------------------------------------------------------
// C = act(A[M,K] @ W[K,N] + b), fp32 vector GEMM.
// 128x128 tile, 256 threads, 8x8 micro-tile, BK=8.
// ---------------------------------------------------------------------------
#define GBM 128
#define GBN 128
#define GBK 8
__global__ __launch_bounds__(256) void gemm_bias_act_kernel(
    const float* __restrict__ A, const float* __restrict__ W,
    const float* __restrict__ bias, float* __restrict__ C,
    int M, int N, int K, int relu)
{
  __shared__ float As[GBK][GBM];
  __shared__ float Bs[GBK][GBN];
  const int tid = threadIdx.x;
  const int row0 = blockIdx.x * GBM;
  const int col0 = blockIdx.y * GBN;
  const int ty = tid >> 4, tx = tid & 15;

  const int arow  = tid >> 1;
  const int acol4 = (tid & 1) * 4;
  const int brow  = tid >> 5;
  const int bcol4 = (tid & 31) * 4;

  float acc[8][8];
  #pragma unroll
  for (int i = 0; i < 8; ++i)
    #pragma unroll
    for (int j = 0; j < 8; ++j) acc[i][j] = 0.0f;

  for (int k0 = 0; k0 < K; k0 += GBK) {
    float4 av = *(const float4*)&A[(size_t)(row0 + arow) * K + k0 + acol4];
    float4 bv = *(const float4*)&W[(size_t)(k0 + brow) * N + col0 + bcol4];
    __syncthreads();
    As[acol4 + 0][arow] = av.x;
    As[acol4 + 1][arow] = av.y;
    As[acol4 + 2][arow] = av.z;
    As[acol4 + 3][arow] = av.w;
    *(float4*)&Bs[brow][bcol4] = bv;
    __syncthreads();
    #pragma unroll
    for (int k = 0; k < GBK; ++k) {
      float a[8], b[8];
      *(float4*)&a[0] = *(const float4*)&As[k][ty * 8 + 0];
      *(float4*)&a[4] = *(const float4*)&As[k][ty * 8 + 4];
      *(float4*)&b[0] = *(const float4*)&Bs[k][tx * 8 + 0];
      *(float4*)&b[4] = *(const float4*)&Bs[k][tx * 8 + 4];
      #pragma unroll
      for (int i = 0; i < 8; ++i)
        #pragma unroll
        for (int j = 0; j < 8; ++j)
          acc[i][j] = fmaf(a[i], b[j], acc[i][j]);
    }
  }

  #pragma unroll
  for (int i = 0; i < 8; ++i) {
    size_t r = (size_t)(row0 + ty * 8 + i);
    #pragma unroll
    for (int j = 0; j < 8; ++j) {
      int c = col0 + tx * 8 + j;
      float v = acc[i][j] + bias[c];
      if (relu) v = fmaxf(v, 0.0f);
      C[r * N + c] = v;
    }
  }
}

// ---------------------------------------------------------------------------
// out[r, :] = h2[r, :] @ W3[256,3] + b3 + res[r, :]   (wave per row)
// ---------------------------------------------------------------------------
__global__ __launch_bounds__(256) void final_kernel(
    const float* __restrict__ h2, const float* __restrict__ W3,
    const float* __restrict__ b3, const float* __restrict__ res,
    float* __restrict__ out, int M)
{
  __shared__ float sW3[768];
  const int tid = threadIdx.x;
  for (int i = tid; i < 768; i += 256) sW3[i] = W3[i];
  __syncthreads();

  const int wave = tid >> 6, lane = tid & 63;
  const int r = blockIdx.x * 4 + wave;
  if (r >= M) return;

  float4 h = ((const float4*)h2)[(size_t)r * 64 + lane];
  const int c = lane * 4;
  float a0 = h.x * sW3[(c + 0) * 3 + 0] + h.y * sW3[(c + 1) * 3 + 0]
           + h.z * sW3[(c + 2) * 3 + 0] + h.w * sW3[(c + 3) * 3 + 0];
  float a1 = h.x * sW3[(c + 0) * 3 + 1] + h.y * sW3[(c + 1) * 3 + 1]
           + h.z * sW3[(c + 2) * 3 + 1] + h.w * sW3[(c + 3) * 3 + 1];
  float a2 = h.x * sW3[(c + 0) * 3 + 2] + h.y * sW3[(c + 1) * 3 + 2]
           + h.z * sW3[(c + 2) * 3 + 2] + h.w * sW3[(c + 3) * 3 + 2];

  #pragma unroll
  for (int off = 32; off; off >>= 1) {
    a0 += __shfl_xor(a0, off);
    a1 += __shfl_xor(a1, off);
    a2 += __shfl_xor(a2, off);
  }
  if (lane == 0) {
    out[(size_t)r * 3 + 0] = a0 + b3[0] + res[(size_t)r * 3 + 0];
    out[(size_t)r * 3 + 1] = a1 + b3[1] + res[(size_t)r * 3 + 1];
    out[(size_t)r * 3 + 2] = a2 + b3[2] + res[(size_t)r * 3 + 2];
  }
}

// ---------------------------------------------------------------------------
extern "C" void kernel_launch(void* const* d_in, const int* in_sizes, int n_in,
                              void* d_out, int out_size, void* d_ws, size_t ws_size,
                              hipStream_t stream) {
  (void)in_sizes; (void)n_in; (void)out_size; (void)ws_size;
  const float* emb1   = (const float*)d_in[0];
  const float* l_y1   = (const float*)d_in[1];
  const float* l_pos1 = (const float*)d_in[2];
  const float* h_pos1 = (const float*)d_in[3];
  const float* emb2   = (const float*)d_in[4];
  const float* l_y2   = (const float*)d_in[5];
  const float* l_pos2 = (const float*)d_in[6];
  const float* h_pos2 = (const float*)d_in[7];
  const float* W1     = (const float*)d_in[8];
  const float* b1     = (const float*)d_in[9];
  const float* W2     = (const float*)d_in[10];
  const float* b2     = (const float*)d_in[11];
  const float* W3     = (const float*)d_in[12];
  const float* b3     = (const float*)d_in[13];
  float* out = (float*)d_out;

  const int Nh = 16384, Nl = 4096, H = 256;
  const int G1 = 16, G2 = 8;          // grid dims: 16^3 for 16384 pts, 8^3 for 4096
  const int M1 = G1 * G1 * G1, M2 = G2 * G2 * G2;

  // ---- workspace carve-up (sequential bump allocator, 256B aligned) ----
  char* wsp = (char*)d_ws;
  size_t off = 0;
  auto alloc = [&](size_t bytes) -> void* {
    void* p = wsp + off;
    off += (bytes + 255) & ~(size_t)255;
    return p;
  };
  int*    idxA    = (int*)   alloc((size_t)Nh * 3 * 4);
  float*  wA      = (float*) alloc((size_t)Nh * 3 * 4);
  float*  tbuf    = (float*) alloc((size_t)Nh * H * 4);   // 16 MB (also h2)
  float*  h1      = (float*) alloc((size_t)Nh * H * 4);   // 16 MB
  float*  h2      = tbuf;
  float*  diff    = (float*) alloc((size_t)Nl * 3 * 4);
  float*  res     = (float*) alloc((size_t)Nh * 3 * 4);
  int*    cnts    = (int*)   alloc((size_t)(M1 + M2 + M2) * 4);  // contiguous: 1 memset
  int*    cnt1 = cnts, *cnt2 = cnts + M1, *cnt3 = cnts + M1 + M2;
  int*    offs1   = (int*)   alloc((size_t)(M1 + 1) * 4);
  int*    cur1    = (int*)   alloc((size_t)M1 * 4);
  int*    offs2   = (int*)   alloc((size_t)(M2 + 1) * 4);
  int*    cur2    = (int*)   alloc((size_t)M2 * 4);
  int*    offs3   = (int*)   alloc((size_t)(M2 + 1) * 4);
  int*    cur3    = (int*)   alloc((size_t)M2 * 4);
  float4* spts1   = (float4*)alloc((size_t)Nh * 16);
  int*    sidx1   = (int*)   alloc((size_t)Nh * 4);
  float4* spts2   = (float4*)alloc((size_t)Nl * 16);
  int*    sidx2   = (int*)   alloc((size_t)Nl * 4);
  float4* spts3   = (float4*)alloc((size_t)Nl * 16);
  int*    sidx3   = (int*)   alloc((size_t)Nl * 4);

  // ---- build the 3 source grids ----
  hipMemsetAsync(cnts, 0, (size_t)(M1 + M2 + M2) * 4, stream);
  cell_count3_kernel<<<96, 256, 0, stream>>>(
      h_pos2, Nh, G1, cnt1,  l_pos2, Nl, G2, cnt2,  l_pos1, Nl, G2, cnt3);
  prefix3_kernel<<<3, 256, 0, stream>>>(
      cnt1, offs1, cur1,  cnt2, offs2, cur2,  cnt3, offs3, cur3);
  scatter3_kernel<<<96, 256, 0, stream>>>(
      h_pos2, Nh, G1, cur1, spts1, sidx1,
      l_pos2, Nl, G2, cur2, spts2, sidx2,
      l_pos1, Nl, G2, cur3, spts3, sidx3);

  // ---- branch 1: x = mlp(emb1 - interp(emb2; h_pos2 -> h_pos1)) ----
  knn_grid_kernel<<<Nh / 64, 64, 0, stream>>>(
      h_pos1, Nh, G1, offs1, spts1, sidx1,
      0, nullptr, nullptr, wA, idxA, nullptr);
  build_t_kernel<<<Nh * 64 / 256, 256, 0, stream>>>(
      emb1, emb2, wA, idxA, tbuf, Nh);
  gemm_bias_act_kernel<<<dim3(Nh / GBM, H / GBN), 256, 0, stream>>>(
      tbuf, W1, b1, h1, Nh, H, H, 1);
  gemm_bias_act_kernel<<<dim3(Nh / GBM, H / GBN), 256, 0, stream>>>(
      h1, W2, b2, h2, Nh, H, H, 1);

  // ---- branch 2: res = interp(l_y1 - interp(l_y2; l_pos2->l_pos1); l_pos1->h_pos1) ----
  knn_grid_kernel<<<Nl / 64, 64, 0, stream>>>(
      l_pos1, Nl, G2, offs2, spts2, sidx2,
      1, l_y1, l_y2, nullptr, nullptr, diff);
  knn_grid_kernel<<<Nh / 64, 64, 0, stream>>>(
      h_pos1, Nh, G2, offs3, spts3, sidx3,
      2, nullptr, diff, nullptr, nullptr, res);

  // ---- final: out = (h2 @ W3 + b3) + res ----
  final_kernel<<<Nh / 4, 256, 0, stream>>>(h2, W3, b3, res, out, Nh);
}

// Round 8
// 212.430 us; speedup vs baseline: 2.4080x; 2.4080x over previous
//
#include <hip/hip_runtime.h>
#include <math.h>

#define BIGF 3.0e38f

// ===========================================================================
// Spatial-hash KNN (K=3), wave-per-query.
// Selection must replicate the np reference's fp32 expansion distance:
//   sx  = (x*x + y*y) + z*z            (sequential, individually rounded)
//   dot = (p0 + p1) + p2, p_k = q_k*s_k
//   d2  = (sy + sx) - 2*dot
// evaluated with fp contract(off) — hipcc's default -ffp-contract=fast
// selects different neighbors (verified rounds 3-6). DO NOT TOUCH.
// Tie-break: lexicographic (d, idx) == stable top_k smallest-index-first;
// also makes the result independent of atomic scatter order.
// ===========================================================================

__device__ __forceinline__ int cell_clamp(float v, int G) {
  int c = (int)(v * (float)G);
  return min(G - 1, max(0, c));
}

// lex (d, idx) top-3 insert, branchless
__device__ __forceinline__ void ins3(float d, int id,
                                     float& d0, float& d1, float& d2,
                                     int& i0, int& i1, int& i2) {
  bool l0 = (d < d0) || (d == d0 && id < i0);
  bool l1 = (d < d1) || (d == d1 && id < i1);
  bool l2 = (d < d2) || (d == d2 && id < i2);
  float nd0 = l0 ? d  : d0;  int ni0 = l0 ? id : i0;
  float nd1 = l0 ? d0 : (l1 ? d  : d1);
  int   ni1 = l0 ? i0 : (l1 ? id : i1);
  float nd2 = l1 ? d1 : (l2 ? d  : d2);
  int   ni2 = l1 ? i1 : (l2 ? id : i2);
  d0 = nd0; d1 = nd1; d2 = nd2; i0 = ni0; i1 = ni1; i2 = ni2;
}

// ---- count: 3 point sets in one dispatch (blocks 0-63 / 64-79 / 80-95) ----
__global__ __launch_bounds__(256) void cell_count3_kernel(
    const float* __restrict__ p1, int n1, int g1, int* __restrict__ c1,
    const float* __restrict__ p2, int n2, int g2, int* __restrict__ c2,
    const float* __restrict__ p3, int n3, int g3, int* __restrict__ c3)
{
  int b = blockIdx.x;
  const float* p; int n, G; int* cnt; int i;
  if (b < 64)      { p = p1; n = n1; G = g1; cnt = c1; i = b * 256 + threadIdx.x; }
  else if (b < 80) { p = p2; n = n2; G = g2; cnt = c2; i = (b - 64) * 256 + threadIdx.x; }
  else             { p = p3; n = n3; G = g3; cnt = c3; i = (b - 80) * 256 + threadIdx.x; }
  if (i >= n) return;
  int cx = cell_clamp(p[3 * i],     G);
  int cy = cell_clamp(p[3 * i + 1], G);
  int cz = cell_clamp(p[3 * i + 2], G);
  atomicAdd(&cnt[(cz * G + cy) * G + cx], 1);
}

// ---- exclusive prefix over 3 grids (block 0: M=4096, blocks 1,2: M=512) ---
__global__ __launch_bounds__(256) void prefix3_kernel(
    const int* __restrict__ c1, int* __restrict__ o1, int* __restrict__ u1,
    const int* __restrict__ c2, int* __restrict__ o2, int* __restrict__ u2,
    const int* __restrict__ c3, int* __restrict__ o3, int* __restrict__ u3)
{
  const int* cnt; int* offs; int* cur; int M;
  if (blockIdx.x == 0)      { cnt = c1; offs = o1; cur = u1; M = 4096; }
  else if (blockIdx.x == 1) { cnt = c2; offs = o2; cur = u2; M = 512; }
  else                      { cnt = c3; offs = o3; cur = u3; M = 512; }
  __shared__ int ps[256];
  const int tid = threadIdx.x;
  const int per = M >> 8;
  const int base = tid * per;
  int s = 0;
  for (int j = 0; j < per; ++j) s += cnt[base + j];
  ps[tid] = s;
  __syncthreads();
  for (int off = 1; off < 256; off <<= 1) {
    int v = (tid >= off) ? ps[tid - off] : 0;
    __syncthreads();
    ps[tid] += v;
    __syncthreads();
  }
  int run = (tid > 0) ? ps[tid - 1] : 0;
  for (int j = 0; j < per; ++j) {
    offs[base + j] = run; cur[base + j] = run;
    run += cnt[base + j];
  }
  if (tid == 255) offs[M] = run;
}

// ---- scatter: sorted float4(x,y,z,sx) + original index -------------------
__global__ __launch_bounds__(256) void scatter3_kernel(
    const float* __restrict__ p1, int n1, int g1, int* __restrict__ u1, float4* __restrict__ s1, int* __restrict__ x1,
    const float* __restrict__ p2, int n2, int g2, int* __restrict__ u2, float4* __restrict__ s2, int* __restrict__ x2,
    const float* __restrict__ p3, int n3, int g3, int* __restrict__ u3, float4* __restrict__ s3, int* __restrict__ x3)
{
  #pragma clang fp contract(off)
  int b = blockIdx.x;
  const float* p; int n, G; int* cur; float4* spts; int* sidx; int i;
  if (b < 64)      { p = p1; n = n1; G = g1; cur = u1; spts = s1; sidx = x1; i = b * 256 + threadIdx.x; }
  else if (b < 80) { p = p2; n = n2; G = g2; cur = u2; spts = s2; sidx = x2; i = (b - 64) * 256 + threadIdx.x; }
  else             { p = p3; n = n3; G = g3; cur = u3; spts = s3; sidx = x3; i = (b - 80) * 256 + threadIdx.x; }
  if (i >= n) return;
  float x = p[3 * i], y = p[3 * i + 1], z = p[3 * i + 2];
  int cx = cell_clamp(x, G), cy = cell_clamp(y, G), cz = cell_clamp(z, G);
  int c = (cz * G + cy) * G + cx;
  int pos = atomicAdd(&cur[c], 1);
  float sx = (x * x + y * y) + z * z;   // sequential, no contraction
  spts[pos] = make_float4(x, y, z, sx);
  sidx[pos] = i;
}

// ---- query: WAVE per query. Lanes split cells of the Chebyshev-R box,
// keep disjoint local lex top-3s, butterfly-merge for stop test / result.
// mode 0: write w[Nq,3], idx[Nq,3]
// mode 1: out3 = base3 - sum_k w_k * feat3[idx_k]
// mode 2: out3 =         sum_k w_k * feat3[idx_k]
__global__ __launch_bounds__(256) void knn_wave_kernel(
    const float* __restrict__ qpos, int Nq, int G,
    const int* __restrict__ offs,
    const float4* __restrict__ spts,
    const int* __restrict__ sidx,
    int mode,
    const float* __restrict__ base3,
    const float* __restrict__ feat3,
    float* __restrict__ w_out, int* __restrict__ i_out,
    float* __restrict__ out3)
{
  #pragma clang fp contract(off)
  const int lane = threadIdx.x & 63;
  const int q = blockIdx.x * (blockDim.x >> 6) + (threadIdx.x >> 6);
  if (q >= Nq) return;

  const float qx = qpos[3 * q], qy = qpos[3 * q + 1], qz = qpos[3 * q + 2];
  const float sy = (qx * qx + qy * qy) + qz * qz;  // sequential, no contraction
  const float cs = 1.0f / (float)G;
  const int cx = cell_clamp(qx, G), cy = cell_clamp(qy, G), cz = cell_clamp(qz, G);

  // per-lane local top-3 over this lane's (disjoint) candidate set
  float d0 = BIGF, d1 = BIGF, d2v = BIGF;
  int i0 = -1, i1 = -1, i2 = -1;
  // merged (global) top-3
  float e0, e1, e2; int j0, j1, j2;

  for (int R = 1; ; ++R) {
    const int W = 2 * R + 1;
    const int ncells = W * W * W;
    for (int m = lane; m < ncells; m += 64) {
      int a = m % W;
      int t = m / W;
      int b = t % W;
      int c = t / W;
      int dx = a - R, dy = b - R, dz = c - R;
      int adx = dx < 0 ? -dx : dx, ady = dy < 0 ? -dy : dy, adz = dz < 0 ? -dz : dz;
      int cheb = max(adx, max(ady, adz));
      if (R > 1 && cheb < R) continue;          // inner box already done
      int xx = cx + dx, yy = cy + dy, zz = cz + dz;
      if (xx < 0 || xx >= G || yy < 0 || yy >= G || zz < 0 || zz >= G) continue;
      int cell = (zz * G + yy) * G + xx;
      int js = offs[cell], je = offs[cell + 1];
      for (int j = js; j < je; ++j) {
        float4 s = spts[j];
        float p0 = qx * s.x, p1 = qy * s.y, p2 = qz * s.z;
        float dt = (p0 + p1) + p2;
        float S  = sy + s.w;
        float dd = S - 2.0f * dt;
        ins3(dd, sidx[j], d0, d1, d2v, i0, i1, i2);
      }
    }
    // butterfly merge a COPY (locals keep accumulating across shells;
    // lanes' local sets stay disjoint so no duplicate corruption)
    e0 = d0; e1 = d1; e2 = d2v; j0 = i0; j1 = i1; j2 = i2;
    #pragma unroll
    for (int msk = 1; msk < 64; msk <<= 1) {
      float o0 = __shfl_xor(e0, msk), o1 = __shfl_xor(e1, msk), o2 = __shfl_xor(e2, msk);
      int   p0 = __shfl_xor(j0, msk), p1 = __shfl_xor(j1, msk), p2 = __shfl_xor(j2, msk);
      ins3(o0, p0, e0, e1, e2, j0, j1, j2);
      ins3(o1, p1, e0, e1, e2, j0, j1, j2);
      ins3(o2, p2, e0, e1, e2, j0, j1, j2);
    }
    // cells at Chebyshev >= R+1 hold points with true d >= R*cs; expansion-d
    // differs from true-d by <= ~1.2e-7 -> margin 1e-6 keeps it conservative.
    float bnd = (float)R * cs;
    if (e2 <= bnd * bnd - 1e-6f || R >= G) break;
  }

  if (lane == 0) {
    float w0 = 1.0f / fmaxf(e0, 1e-16f);
    float w1 = 1.0f / fmaxf(e1, 1e-16f);
    float w2 = 1.0f / fmaxf(e2, 1e-16f);
    float inv = 1.0f / (w0 + w1 + w2);
    w0 *= inv; w1 *= inv; w2 *= inv;
    if (mode == 0) {
      w_out[(size_t)q * 3 + 0] = w0; w_out[(size_t)q * 3 + 1] = w1; w_out[(size_t)q * 3 + 2] = w2;
      i_out[(size_t)q * 3 + 0] = j0; i_out[(size_t)q * 3 + 1] = j1; i_out[(size_t)q * 3 + 2] = j2;
    } else {
      #pragma unroll
      for (int f = 0; f < 3; ++f) {
        float v = w0 * feat3[(size_t)j0 * 3 + f]
                + w1 * feat3[(size_t)j1 * 3 + f]
                + w2 * feat3[(size_t)j2 * 3 + f];
        out3[(size_t)q * 3 + f] = (mode == 1) ? (base3[(size_t)q * 3 + f] - v) : v;
      }
    }
  }
}

// ---------------------------------------------------------------------------
// t[q, :] = emb1[q, :] - sum_k w_k * emb2[idx_k, :]     (F = 256, float4)
// ---------------------------------------------------------------------------
__global__ __launch_bounds__(256) void build_t_kernel(
    const float* __restrict__ emb1, const float* __restrict__ emb2,
    const float* __restrict__ w, const int* __restrict__ idx,
    float* __restrict__ t, int Nq)
{
  int gid = blockIdx.x * 256 + threadIdx.x;
  int q = gid >> 6, c4 = gid & 63;
  if (q >= Nq) return;
  float w0 = w[(size_t)q * 3 + 0], w1 = w[(size_t)q * 3 + 1], w2 = w[(size_t)q * 3 + 2];
  int i0 = idx[(size_t)q * 3 + 0], i1 = idx[(size_t)q * 3 + 1], i2 = idx[(size_t)q * 3 + 2];
  const float4* e1 = (const float4*)emb1;
  const float4* e2 = (const float4*)emb2;
  float4 a  = e1[(size_t)q * 64 + c4];
  float4 f0 = e2[(size_t)i0 * 64 + c4];
  float4 f1 = e2[(size_t)i1 * 64 + c4];
  float4 f2 = e2[(size_t)i2 * 64 + c4];
  float4 r;
  r.x = a.x - (w0 * f0.x + w1 * f1.x + w2 * f2.x);
  r.y = a.y - (w0 * f0.y + w1 * f1.y + w2 * f2.y);
  r.z = a.z - (w0 * f0.z + w1 * f1.z + w2 * f2.z);
  r.w = a.w - (w0 * f0.w + w1 * f1.w + w2 * f2.w);
  ((float4*)t)[(size_t)q * 64 + c4] = r;
}

// ---------------------------------------------------------------------------
// C = act(A[M,K] @ W[K,N] + b), fp32 vector GEMM.
// 128x128 tile, 256 threads, 8x8 micro-tile, BK=8.
// ---------------------------------------------------------------------------
#define GBM 128
#define GBN 128
#define GBK 8
__global__ __launch_bounds__(256) void gemm_bias_act_kernel(
    const float* __restrict__ A, const float* __restrict__ W,
    const float* __restrict__ bias, float* __restrict__ C,
    int M, int N, int K, int relu)
{
  __shared__ float As[GBK][GBM];
  __shared__ float Bs[GBK][GBN];
  const int tid = threadIdx.x;
  const int row0 = blockIdx.x * GBM;
  const int col0 = blockIdx.y * GBN;
  const int ty = tid >> 4, tx = tid & 15;

  const int arow  = tid >> 1;
  const int acol4 = (tid & 1) * 4;
  const int brow  = tid >> 5;
  const int bcol4 = (tid & 31) * 4;

  float acc[8][8];
  #pragma unroll
  for (int i = 0; i < 8; ++i)
    #pragma unroll
    for (int j = 0; j < 8; ++j) acc[i][j] = 0.0f;

  for (int k0 = 0; k0 < K; k0 += GBK) {
    float4 av = *(const float4*)&A[(size_t)(row0 + arow) * K + k0 + acol4];
    float4 bv = *(const float4*)&W[(size_t)(k0 + brow) * N + col0 + bcol4];
    __syncthreads();
    As[acol4 + 0][arow] = av.x;
    As[acol4 + 1][arow] = av.y;
    As[acol4 + 2][arow] = av.z;
    As[acol4 + 3][arow] = av.w;
    *(float4*)&Bs[brow][bcol4] = bv;
    __syncthreads();
    #pragma unroll
    for (int k = 0; k < GBK; ++k) {
      float a[8], b[8];
      *(float4*)&a[0] = *(const float4*)&As[k][ty * 8 + 0];
      *(float4*)&a[4] = *(const float4*)&As[k][ty * 8 + 4];
      *(float4*)&b[0] = *(const float4*)&Bs[k][tx * 8 + 0];
      *(float4*)&b[4] = *(const float4*)&Bs[k][tx * 8 + 4];
      #pragma unroll
      for (int i = 0; i < 8; ++i)
        #pragma unroll
        for (int j = 0; j < 8; ++j)
          acc[i][j] = fmaf(a[i], b[j], acc[i][j]);
    }
  }

  #pragma unroll
  for (int i = 0; i < 8; ++i) {
    size_t r = (size_t)(row0 + ty * 8 + i);
    #pragma unroll
    for (int j = 0; j < 8; ++j) {
      int c = col0 + tx * 8 + j;
      float v = acc[i][j] + bias[c];
      if (relu) v = fmaxf(v, 0.0f);
      C[r * N + c] = v;
    }
  }
}

// ---------------------------------------------------------------------------
// out[r, :] = h2[r, :] @ W3[256,3] + b3 + res[r, :]   (wave per row)
// ---------------------------------------------------------------------------
__global__ __launch_bounds__(256) void final_kernel(
    const float* __restrict__ h2, const float* __restrict__ W3,
    const float* __restrict__ b3, const float* __restrict__ res,
    float* __restrict__ out, int M)
{
  __shared__ float sW3[768];
  const int tid = threadIdx.x;
  for (int i = tid; i < 768; i += 256) sW3[i] = W3[i];
  __syncthreads();

  const int wave = tid >> 6, lane = tid & 63;
  const int r = blockIdx.x * 4 + wave;
  if (r >= M) return;

  float4 h = ((const float4*)h2)[(size_t)r * 64 + lane];
  const int c = lane * 4;
  float a0 = h.x * sW3[(c + 0) * 3 + 0] + h.y * sW3[(c + 1) * 3 + 0]
           + h.z * sW3[(c + 2) * 3 + 0] + h.w * sW3[(c + 3) * 3 + 0];
  float a1 = h.x * sW3[(c + 0) * 3 + 1] + h.y * sW3[(c + 1) * 3 + 1]
           + h.z * sW3[(c + 2) * 3 + 1] + h.w * sW3[(c + 3) * 3 + 1];
  float a2 = h.x * sW3[(c + 0) * 3 + 2] + h.y * sW3[(c + 1) * 3 + 2]
           + h.z * sW3[(c + 2) * 3 + 2] + h.w * sW3[(c + 3) * 3 + 2];

  #pragma unroll
  for (int off = 32; off; off >>= 1) {
    a0 += __shfl_xor(a0, off);
    a1 += __shfl_xor(a1, off);
    a2 += __shfl_xor(a2, off);
  }
  if (lane == 0) {
    out[(size_t)r * 3 + 0] = a0 + b3[0] + res[(size_t)r * 3 + 0];
    out[(size_t)r * 3 + 1] = a1 + b3[1] + res[(size_t)r * 3 + 1];
    out[(size_t)r * 3 + 2] = a2 + b3[2] + res[(size_t)r * 3 + 2];
  }
}

// ---------------------------------------------------------------------------
extern "C" void kernel_launch(void* const* d_in, const int* in_sizes, int n_in,
                              void* d_out, int out_size, void* d_ws, size_t ws_size,
                              hipStream_t stream) {
  (void)in_sizes; (void)n_in; (void)out_size; (void)ws_size;
  const float* emb1   = (const float*)d_in[0];
  const float* l_y1   = (const float*)d_in[1];
  const float* l_pos1 = (const float*)d_in[2];
  const float* h_pos1 = (const float*)d_in[3];
  const float* emb2   = (const float*)d_in[4];
  const float* l_y2   = (const float*)d_in[5];
  const float* l_pos2 = (const float*)d_in[6];
  const float* h_pos2 = (const float*)d_in[7];
  const float* W1     = (const float*)d_in[8];
  const float* b1     = (const float*)d_in[9];
  const float* W2     = (const float*)d_in[10];
  const float* b2     = (const float*)d_in[11];
  const float* W3     = (const float*)d_in[12];
  const float* b3     = (const float*)d_in[13];
  float* out = (float*)d_out;

  const int Nh = 16384, Nl = 4096, H = 256;
  const int G1 = 16, G2 = 8;
  const int M1 = G1 * G1 * G1, M2 = G2 * G2 * G2;

  // ---- workspace carve-up (sequential bump allocator, 256B aligned) ----
  char* wsp = (char*)d_ws;
  size_t off = 0;
  auto alloc = [&](size_t bytes) -> void* {
    void* p = wsp + off;
    off += (bytes + 255) & ~(size_t)255;
    return p;
  };
  int*    idxA    = (int*)   alloc((size_t)Nh * 3 * 4);
  float*  wA      = (float*) alloc((size_t)Nh * 3 * 4);
  float*  tbuf    = (float*) alloc((size_t)Nh * H * 4);   // 16 MB (also h2)
  float*  h1      = (float*) alloc((size_t)Nh * H * 4);   // 16 MB
  float*  h2      = tbuf;
  float*  diff    = (float*) alloc((size_t)Nl * 3 * 4);
  float*  res     = (float*) alloc((size_t)Nh * 3 * 4);
  int*    cnts    = (int*)   alloc((size_t)(M1 + M2 + M2) * 4);
  int*    cnt1 = cnts, *cnt2 = cnts + M1, *cnt3 = cnts + M1 + M2;
  int*    offs1   = (int*)   alloc((size_t)(M1 + 1) * 4);
  int*    cur1    = (int*)   alloc((size_t)M1 * 4);
  int*    offs2   = (int*)   alloc((size_t)(M2 + 1) * 4);
  int*    cur2    = (int*)   alloc((size_t)M2 * 4);
  int*    offs3   = (int*)   alloc((size_t)(M2 + 1) * 4);
  int*    cur3    = (int*)   alloc((size_t)M2 * 4);
  float4* spts1   = (float4*)alloc((size_t)Nh * 16);
  int*    sidx1   = (int*)   alloc((size_t)Nh * 4);
  float4* spts2   = (float4*)alloc((size_t)Nl * 16);
  int*    sidx2   = (int*)   alloc((size_t)Nl * 4);
  float4* spts3   = (float4*)alloc((size_t)Nl * 16);
  int*    sidx3   = (int*)   alloc((size_t)Nl * 4);

  // ---- build the 3 source grids ----
  hipMemsetAsync(cnts, 0, (size_t)(M1 + M2 + M2) * 4, stream);
  cell_count3_kernel<<<96, 256, 0, stream>>>(
      h_pos2, Nh, G1, cnt1,  l_pos2, Nl, G2, cnt2,  l_pos1, Nl, G2, cnt3);
  prefix3_kernel<<<3, 256, 0, stream>>>(
      cnt1, offs1, cur1,  cnt2, offs2, cur2,  cnt3, offs3, cur3);
  scatter3_kernel<<<96, 256, 0, stream>>>(
      h_pos2, Nh, G1, cur1, spts1, sidx1,
      l_pos2, Nl, G2, cur2, spts2, sidx2,
      l_pos1, Nl, G2, cur3, spts3, sidx3);

  // ---- branch 1: x = mlp(emb1 - interp(emb2; h_pos2 -> h_pos1)) ----
  knn_wave_kernel<<<Nh / 4, 256, 0, stream>>>(
      h_pos1, Nh, G1, offs1, spts1, sidx1,
      0, nullptr, nullptr, wA, idxA, nullptr);
  build_t_kernel<<<Nh * 64 / 256, 256, 0, stream>>>(
      emb1, emb2, wA, idxA, tbuf, Nh);
  gemm_bias_act_kernel<<<dim3(Nh / GBM, H / GBN), 256, 0, stream>>>(
      tbuf, W1, b1, h1, Nh, H, H, 1);
  gemm_bias_act_kernel<<<dim3(Nh / GBM, H / GBN), 256, 0, stream>>>(
      h1, W2, b2, h2, Nh, H, H, 1);

  // ---- branch 2: res = interp(l_y1 - interp(l_y2; l_pos2->l_pos1); l_pos1->h_pos1) ----
  knn_wave_kernel<<<Nl / 4, 256, 0, stream>>>(
      l_pos1, Nl, G2, offs2, spts2, sidx2,
      1, l_y1, l_y2, nullptr, nullptr, diff);
  knn_wave_kernel<<<Nh / 4, 256, 0, stream>>>(
      h_pos1, Nh, G2, offs3, spts3, sidx3,
      2, nullptr, diff, nullptr, nullptr, res);

  // ---- final: out = (h2 @ W3 + b3) + res ----
  final_kernel<<<Nh / 4, 256, 0, stream>>>(h2, W3, b3, res, out, Nh);
}

// Round 9
// 188.197 us; speedup vs baseline: 2.7180x; 1.1288x over previous
//
#include <hip/hip_runtime.h>
#include <math.h>

#define BIGF 3.0e38f

// ===========================================================================
// Spatial-hash KNN (K=3), wave-per-query.
// Selection must replicate the np reference's fp32 expansion distance:
//   sx  = (x*x + y*y) + z*z            (sequential, individually rounded)
//   dot = (p0 + p1) + p2, p_k = q_k*s_k
//   d2  = (sy + sx) - 2*dot
// evaluated with fp contract(off) — hipcc's default -ffp-contract=fast
// selects different neighbors (verified rounds 3-6). DO NOT TOUCH.
// Tie-break: lexicographic (d, idx) == stable top_k smallest-index-first;
// also makes the result independent of atomic scatter order.
// ===========================================================================

__device__ __forceinline__ int cell_clamp(float v, int G) {
  int c = (int)(v * (float)G);
  return min(G - 1, max(0, c));
}

// lex (d, idx) top-3 insert, branchless
__device__ __forceinline__ void ins3(float d, int id,
                                     float& d0, float& d1, float& d2,
                                     int& i0, int& i1, int& i2) {
  bool l0 = (d < d0) || (d == d0 && id < i0);
  bool l1 = (d < d1) || (d == d1 && id < i1);
  bool l2 = (d < d2) || (d == d2 && id < i2);
  float nd0 = l0 ? d  : d0;  int ni0 = l0 ? id : i0;
  float nd1 = l0 ? d0 : (l1 ? d  : d1);
  int   ni1 = l0 ? i0 : (l1 ? id : i1);
  float nd2 = l1 ? d1 : (l2 ? d  : d2);
  int   ni2 = l1 ? i1 : (l2 ? id : i2);
  d0 = nd0; d1 = nd1; d2 = nd2; i0 = ni0; i1 = ni1; i2 = ni2;
}

// ---- count: 3 point sets in one dispatch (blocks 0-63 / 64-79 / 80-95) ----
__global__ __launch_bounds__(256) void cell_count3_kernel(
    const float* __restrict__ p1, int n1, int g1, int* __restrict__ c1,
    const float* __restrict__ p2, int n2, int g2, int* __restrict__ c2,
    const float* __restrict__ p3, int n3, int g3, int* __restrict__ c3)
{
  int b = blockIdx.x;
  const float* p; int n, G; int* cnt; int i;
  if (b < 64)      { p = p1; n = n1; G = g1; cnt = c1; i = b * 256 + threadIdx.x; }
  else if (b < 80) { p = p2; n = n2; G = g2; cnt = c2; i = (b - 64) * 256 + threadIdx.x; }
  else             { p = p3; n = n3; G = g3; cnt = c3; i = (b - 80) * 256 + threadIdx.x; }
  if (i >= n) return;
  int cx = cell_clamp(p[3 * i],     G);
  int cy = cell_clamp(p[3 * i + 1], G);
  int cz = cell_clamp(p[3 * i + 2], G);
  atomicAdd(&cnt[(cz * G + cy) * G + cx], 1);
}

// ---- exclusive prefix over 3 grids (block 0: M=4096, blocks 1,2: M=512) ---
__global__ __launch_bounds__(256) void prefix3_kernel(
    const int* __restrict__ c1, int* __restrict__ o1, int* __restrict__ u1,
    const int* __restrict__ c2, int* __restrict__ o2, int* __restrict__ u2,
    const int* __restrict__ c3, int* __restrict__ o3, int* __restrict__ u3)
{
  const int* cnt; int* offs; int* cur; int M;
  if (blockIdx.x == 0)      { cnt = c1; offs = o1; cur = u1; M = 4096; }
  else if (blockIdx.x == 1) { cnt = c2; offs = o2; cur = u2; M = 512; }
  else                      { cnt = c3; offs = o3; cur = u3; M = 512; }
  __shared__ int ps[256];
  const int tid = threadIdx.x;
  const int per = M >> 8;
  const int base = tid * per;
  int s = 0;
  for (int j = 0; j < per; ++j) s += cnt[base + j];
  ps[tid] = s;
  __syncthreads();
  for (int off = 1; off < 256; off <<= 1) {
    int v = (tid >= off) ? ps[tid - off] : 0;
    __syncthreads();
    ps[tid] += v;
    __syncthreads();
  }
  int run = (tid > 0) ? ps[tid - 1] : 0;
  for (int j = 0; j < per; ++j) {
    offs[base + j] = run; cur[base + j] = run;
    run += cnt[base + j];
  }
  if (tid == 255) offs[M] = run;
}

// ---- scatter: sorted float4(x,y,z,sx) + original index -------------------
__global__ __launch_bounds__(256) void scatter3_kernel(
    const float* __restrict__ p1, int n1, int g1, int* __restrict__ u1, float4* __restrict__ s1, int* __restrict__ x1,
    const float* __restrict__ p2, int n2, int g2, int* __restrict__ u2, float4* __restrict__ s2, int* __restrict__ x2,
    const float* __restrict__ p3, int n3, int g3, int* __restrict__ u3, float4* __restrict__ s3, int* __restrict__ x3)
{
  #pragma clang fp contract(off)
  int b = blockIdx.x;
  const float* p; int n, G; int* cur; float4* spts; int* sidx; int i;
  if (b < 64)      { p = p1; n = n1; G = g1; cur = u1; spts = s1; sidx = x1; i = b * 256 + threadIdx.x; }
  else if (b < 80) { p = p2; n = n2; G = g2; cur = u2; spts = s2; sidx = x2; i = (b - 64) * 256 + threadIdx.x; }
  else             { p = p3; n = n3; G = g3; cur = u3; spts = s3; sidx = x3; i = (b - 80) * 256 + threadIdx.x; }
  if (i >= n) return;
  float x = p[3 * i], y = p[3 * i + 1], z = p[3 * i + 2];
  int cx = cell_clamp(x, G), cy = cell_clamp(y, G), cz = cell_clamp(z, G);
  int c = (cz * G + cy) * G + cx;
  int pos = atomicAdd(&cur[c], 1);
  float sx = (x * x + y * y) + z * z;   // sequential, no contraction
  spts[pos] = make_float4(x, y, z, sx);
  sidx[pos] = i;
}

// ---- query: WAVE per query. Lanes split cells of the Chebyshev-R box,
// keep disjoint local lex top-3s, butterfly-merge for stop test / result.
__global__ __launch_bounds__(256) void knn_wave_kernel(
    const float* __restrict__ qpos, int Nq, int G,
    const int* __restrict__ offs,
    const float4* __restrict__ spts,
    const int* __restrict__ sidx,
    int mode,
    const float* __restrict__ base3,
    const float* __restrict__ feat3,
    float* __restrict__ w_out, int* __restrict__ i_out,
    float* __restrict__ out3)
{
  #pragma clang fp contract(off)
  const int lane = threadIdx.x & 63;
  const int q = blockIdx.x * (blockDim.x >> 6) + (threadIdx.x >> 6);
  if (q >= Nq) return;

  const float qx = qpos[3 * q], qy = qpos[3 * q + 1], qz = qpos[3 * q + 2];
  const float sy = (qx * qx + qy * qy) + qz * qz;  // sequential, no contraction
  const float cs = 1.0f / (float)G;
  const int cx = cell_clamp(qx, G), cy = cell_clamp(qy, G), cz = cell_clamp(qz, G);

  float d0 = BIGF, d1 = BIGF, d2v = BIGF;
  int i0 = -1, i1 = -1, i2 = -1;
  float e0, e1, e2; int j0, j1, j2;

  for (int R = 1; ; ++R) {
    const int W = 2 * R + 1;
    const int ncells = W * W * W;
    for (int m = lane; m < ncells; m += 64) {
      int a = m % W;
      int t = m / W;
      int b = t % W;
      int c = t / W;
      int dx = a - R, dy = b - R, dz = c - R;
      int adx = dx < 0 ? -dx : dx, ady = dy < 0 ? -dy : dy, adz = dz < 0 ? -dz : dz;
      int cheb = max(adx, max(ady, adz));
      if (R > 1 && cheb < R) continue;          // inner box already done
      int xx = cx + dx, yy = cy + dy, zz = cz + dz;
      if (xx < 0 || xx >= G || yy < 0 || yy >= G || zz < 0 || zz >= G) continue;
      int cell = (zz * G + yy) * G + xx;
      int js = offs[cell], je = offs[cell + 1];
      for (int j = js; j < je; ++j) {
        float4 s = spts[j];
        float p0 = qx * s.x, p1 = qy * s.y, p2 = qz * s.z;
        float dt = (p0 + p1) + p2;
        float S  = sy + s.w;
        float dd = S - 2.0f * dt;
        ins3(dd, sidx[j], d0, d1, d2v, i0, i1, i2);
      }
    }
    e0 = d0; e1 = d1; e2 = d2v; j0 = i0; j1 = i1; j2 = i2;
    #pragma unroll
    for (int msk = 1; msk < 64; msk <<= 1) {
      float o0 = __shfl_xor(e0, msk), o1 = __shfl_xor(e1, msk), o2 = __shfl_xor(e2, msk);
      int   p0 = __shfl_xor(j0, msk), p1 = __shfl_xor(j1, msk), p2 = __shfl_xor(j2, msk);
      ins3(o0, p0, e0, e1, e2, j0, j1, j2);
      ins3(o1, p1, e0, e1, e2, j0, j1, j2);
      ins3(o2, p2, e0, e1, e2, j0, j1, j2);
    }
    float bnd = (float)R * cs;
    if (e2 <= bnd * bnd - 1e-6f || R >= G) break;
  }

  if (lane == 0) {
    float w0 = 1.0f / fmaxf(e0, 1e-16f);
    float w1 = 1.0f / fmaxf(e1, 1e-16f);
    float w2 = 1.0f / fmaxf(e2, 1e-16f);
    float inv = 1.0f / (w0 + w1 + w2);
    w0 *= inv; w1 *= inv; w2 *= inv;
    if (mode == 0) {
      w_out[(size_t)q * 3 + 0] = w0; w_out[(size_t)q * 3 + 1] = w1; w_out[(size_t)q * 3 + 2] = w2;
      i_out[(size_t)q * 3 + 0] = j0; i_out[(size_t)q * 3 + 1] = j1; i_out[(size_t)q * 3 + 2] = j2;
    } else {
      #pragma unroll
      for (int f = 0; f < 3; ++f) {
        float v = w0 * feat3[(size_t)j0 * 3 + f]
                + w1 * feat3[(size_t)j1 * 3 + f]
                + w2 * feat3[(size_t)j2 * 3 + f];
        out3[(size_t)q * 3 + f] = (mode == 1) ? (base3[(size_t)q * 3 + f] - v) : v;
      }
    }
  }
}

// ---------------------------------------------------------------------------
// t[q, :] = emb1[q, :] - sum_k w_k * emb2[idx_k, :]     (F = 256, float4)
// ---------------------------------------------------------------------------
__global__ __launch_bounds__(256) void build_t_kernel(
    const float* __restrict__ emb1, const float* __restrict__ emb2,
    const float* __restrict__ w, const int* __restrict__ idx,
    float* __restrict__ t, int Nq)
{
  int gid = blockIdx.x * 256 + threadIdx.x;
  int q = gid >> 6, c4 = gid & 63;
  if (q >= Nq) return;
  float w0 = w[(size_t)q * 3 + 0], w1 = w[(size_t)q * 3 + 1], w2 = w[(size_t)q * 3 + 2];
  int i0 = idx[(size_t)q * 3 + 0], i1 = idx[(size_t)q * 3 + 1], i2 = idx[(size_t)q * 3 + 2];
  const float4* e1 = (const float4*)emb1;
  const float4* e2 = (const float4*)emb2;
  float4 a  = e1[(size_t)q * 64 + c4];
  float4 f0 = e2[(size_t)i0 * 64 + c4];
  float4 f1 = e2[(size_t)i1 * 64 + c4];
  float4 f2 = e2[(size_t)i2 * 64 + c4];
  float4 r;
  r.x = a.x - (w0 * f0.x + w1 * f1.x + w2 * f2.x);
  r.y = a.y - (w0 * f0.y + w1 * f1.y + w2 * f2.y);
  r.z = a.z - (w0 * f0.z + w1 * f1.z + w2 * f2.z);
  r.w = a.w - (w0 * f0.w + w1 * f1.w + w2 * f2.w);
  ((float4*)t)[(size_t)q * 64 + c4] = r;
}

// ---------------------------------------------------------------------------
// C = act(A[M,K] @ W[K,N] + b), fp32 vector GEMM, occupancy-tuned for skinny
// output (M large, N=256): 64x64 tile, 4x4 micro-tile, 256 threads, BK=32.
// Grid = (M/64)*(N/64) = 1024 blocks -> 4 blocks/CU = 16 waves/CU.
// LDS padded to 68 (== 4 mod 32): transpose-store aliasing <= 2-way (free).
// ---------------------------------------------------------------------------
#define TBM 64
#define TBN 64
#define TBK 32
__global__ __launch_bounds__(256) void gemm_bias_act_kernel(
    const float* __restrict__ A, const float* __restrict__ W,
    const float* __restrict__ bias, float* __restrict__ C,
    int M, int N, int K, int relu)
{
  __shared__ float As[TBK][68];
  __shared__ float Bs[TBK][68];
  const int tid = threadIdx.x;
  const int row0 = blockIdx.x * TBM;
  const int col0 = blockIdx.y * TBN;
  const int ty = tid >> 4, tx = tid & 15;   // 16x16 threads, 4x4 outputs each

  const int arow  = tid >> 2;               // 0..63
  const int acol4 = (tid & 3) * 4;          // 0,4,8,12  (+16 second half)
  const int brow  = tid >> 4;               // 0..15     (+16 second half)
  const int bcol4 = (tid & 15) * 4;         // 0..60

  float acc[4][4];
  #pragma unroll
  for (int i = 0; i < 4; ++i)
    #pragma unroll
    for (int j = 0; j < 4; ++j) acc[i][j] = 0.0f;

  for (int k0 = 0; k0 < K; k0 += TBK) {
    float4 av0 = *(const float4*)&A[(size_t)(row0 + arow) * K + k0 + acol4];
    float4 av1 = *(const float4*)&A[(size_t)(row0 + arow) * K + k0 + acol4 + 16];
    float4 bv0 = *(const float4*)&W[(size_t)(k0 + brow) * N + col0 + bcol4];
    float4 bv1 = *(const float4*)&W[(size_t)(k0 + brow + 16) * N + col0 + bcol4];
    __syncthreads();
    As[acol4 + 0][arow] = av0.x;
    As[acol4 + 1][arow] = av0.y;
    As[acol4 + 2][arow] = av0.z;
    As[acol4 + 3][arow] = av0.w;
    As[acol4 + 16][arow] = av1.x;
    As[acol4 + 17][arow] = av1.y;
    As[acol4 + 18][arow] = av1.z;
    As[acol4 + 19][arow] = av1.w;
    *(float4*)&Bs[brow][bcol4] = bv0;
    *(float4*)&Bs[brow + 16][bcol4] = bv1;
    __syncthreads();
    #pragma unroll
    for (int k = 0; k < TBK; ++k) {
      float a[4], b[4];
      *(float4*)&a[0] = *(const float4*)&As[k][ty * 4];
      *(float4*)&b[0] = *(const float4*)&Bs[k][tx * 4];
      #pragma unroll
      for (int i = 0; i < 4; ++i)
        #pragma unroll
        for (int j = 0; j < 4; ++j)
          acc[i][j] = fmaf(a[i], b[j], acc[i][j]);
    }
  }

  #pragma unroll
  for (int i = 0; i < 4; ++i) {
    size_t r = (size_t)(row0 + ty * 4 + i);
    int c = col0 + tx * 4;
    float4 v;
    v.x = acc[i][0] + bias[c + 0];
    v.y = acc[i][1] + bias[c + 1];
    v.z = acc[i][2] + bias[c + 2];
    v.w = acc[i][3] + bias[c + 3];
    if (relu) {
      v.x = fmaxf(v.x, 0.0f); v.y = fmaxf(v.y, 0.0f);
      v.z = fmaxf(v.z, 0.0f); v.w = fmaxf(v.w, 0.0f);
    }
    *(float4*)&C[r * N + c] = v;
  }
}

// ---------------------------------------------------------------------------
// out[r, :] = h2[r, :] @ W3[256,3] + b3 + res[r, :]   (wave per row)
// ---------------------------------------------------------------------------
__global__ __launch_bounds__(256) void final_kernel(
    const float* __restrict__ h2, const float* __restrict__ W3,
    const float* __restrict__ b3, const float* __restrict__ res,
    float* __restrict__ out, int M)
{
  __shared__ float sW3[768];
  const int tid = threadIdx.x;
  for (int i = tid; i < 768; i += 256) sW3[i] = W3[i];
  __syncthreads();

  const int wave = tid >> 6, lane = tid & 63;
  const int r = blockIdx.x * 4 + wave;
  if (r >= M) return;

  float4 h = ((const float4*)h2)[(size_t)r * 64 + lane];
  const int c = lane * 4;
  float a0 = h.x * sW3[(c + 0) * 3 + 0] + h.y * sW3[(c + 1) * 3 + 0]
           + h.z * sW3[(c + 2) * 3 + 0] + h.w * sW3[(c + 3) * 3 + 0];
  float a1 = h.x * sW3[(c + 0) * 3 + 1] + h.y * sW3[(c + 1) * 3 + 1]
           + h.z * sW3[(c + 2) * 3 + 1] + h.w * sW3[(c + 3) * 3 + 1];
  float a2 = h.x * sW3[(c + 0) * 3 + 2] + h.y * sW3[(c + 1) * 3 + 2]
           + h.z * sW3[(c + 2) * 3 + 2] + h.w * sW3[(c + 3) * 3 + 2];

  #pragma unroll
  for (int off = 32; off; off >>= 1) {
    a0 += __shfl_xor(a0, off);
    a1 += __shfl_xor(a1, off);
    a2 += __shfl_xor(a2, off);
  }
  if (lane == 0) {
    out[(size_t)r * 3 + 0] = a0 + b3[0] + res[(size_t)r * 3 + 0];
    out[(size_t)r * 3 + 1] = a1 + b3[1] + res[(size_t)r * 3 + 1];
    out[(size_t)r * 3 + 2] = a2 + b3[2] + res[(size_t)r * 3 + 2];
  }
}

// ---------------------------------------------------------------------------
extern "C" void kernel_launch(void* const* d_in, const int* in_sizes, int n_in,
                              void* d_out, int out_size, void* d_ws, size_t ws_size,
                              hipStream_t stream) {
  (void)in_sizes; (void)n_in; (void)out_size; (void)ws_size;
  const float* emb1   = (const float*)d_in[0];
  const float* l_y1   = (const float*)d_in[1];
  const float* l_pos1 = (const float*)d_in[2];
  const float* h_pos1 = (const float*)d_in[3];
  const float* emb2   = (const float*)d_in[4];
  const float* l_y2   = (const float*)d_in[5];
  const float* l_pos2 = (const float*)d_in[6];
  const float* h_pos2 = (const float*)d_in[7];
  const float* W1     = (const float*)d_in[8];
  const float* b1     = (const float*)d_in[9];
  const float* W2     = (const float*)d_in[10];
  const float* b2     = (const float*)d_in[11];
  const float* W3     = (const float*)d_in[12];
  const float* b3     = (const float*)d_in[13];
  float* out = (float*)d_out;

  const int Nh = 16384, Nl = 4096, H = 256;
  const int G1 = 16, G2 = 8;
  const int M1 = G1 * G1 * G1, M2 = G2 * G2 * G2;

  // ---- workspace carve-up (sequential bump allocator, 256B aligned) ----
  char* wsp = (char*)d_ws;
  size_t off = 0;
  auto alloc = [&](size_t bytes) -> void* {
    void* p = wsp + off;
    off += (bytes + 255) & ~(size_t)255;
    return p;
  };
  int*    idxA    = (int*)   alloc((size_t)Nh * 3 * 4);
  float*  wA      = (float*) alloc((size_t)Nh * 3 * 4);
  float*  tbuf    = (float*) alloc((size_t)Nh * H * 4);   // 16 MB (also h2)
  float*  h1      = (float*) alloc((size_t)Nh * H * 4);   // 16 MB
  float*  h2      = tbuf;
  float*  diff    = (float*) alloc((size_t)Nl * 3 * 4);
  float*  res     = (float*) alloc((size_t)Nh * 3 * 4);
  int*    cnts    = (int*)   alloc((size_t)(M1 + M2 + M2) * 4);
  int*    cnt1 = cnts, *cnt2 = cnts + M1, *cnt3 = cnts + M1 + M2;
  int*    offs1   = (int*)   alloc((size_t)(M1 + 1) * 4);
  int*    cur1    = (int*)   alloc((size_t)M1 * 4);
  int*    offs2   = (int*)   alloc((size_t)(M2 + 1) * 4);
  int*    cur2    = (int*)   alloc((size_t)M2 * 4);
  int*    offs3   = (int*)   alloc((size_t)(M2 + 1) * 4);
  int*    cur3    = (int*)   alloc((size_t)M2 * 4);
  float4* spts1   = (float4*)alloc((size_t)Nh * 16);
  int*    sidx1   = (int*)   alloc((size_t)Nh * 4);
  float4* spts2   = (float4*)alloc((size_t)Nl * 16);
  int*    sidx2   = (int*)   alloc((size_t)Nl * 4);
  float4* spts3   = (float4*)alloc((size_t)Nl * 16);
  int*    sidx3   = (int*)   alloc((size_t)Nl * 4);

  // ---- build the 3 source grids ----
  hipMemsetAsync(cnts, 0, (size_t)(M1 + M2 + M2) * 4, stream);
  cell_count3_kernel<<<96, 256, 0, stream>>>(
      h_pos2, Nh, G1, cnt1,  l_pos2, Nl, G2, cnt2,  l_pos1, Nl, G2, cnt3);
  prefix3_kernel<<<3, 256, 0, stream>>>(
      cnt1, offs1, cur1,  cnt2, offs2, cur2,  cnt3, offs3, cur3);
  scatter3_kernel<<<96, 256, 0, stream>>>(
      h_pos2, Nh, G1, cur1, spts1, sidx1,
      l_pos2, Nl, G2, cur2, spts2, sidx2,
      l_pos1, Nl, G2, cur3, spts3, sidx3);

  // ---- branch 1: x = mlp(emb1 - interp(emb2; h_pos2 -> h_pos1)) ----
  knn_wave_kernel<<<Nh / 4, 256, 0, stream>>>(
      h_pos1, Nh, G1, offs1, spts1, sidx1,
      0, nullptr, nullptr, wA, idxA, nullptr);
  build_t_kernel<<<Nh * 64 / 256, 256, 0, stream>>>(
      emb1, emb2, wA, idxA, tbuf, Nh);
  gemm_bias_act_kernel<<<dim3(Nh / TBM, H / TBN), 256, 0, stream>>>(
      tbuf, W1, b1, h1, Nh, H, H, 1);
  gemm_bias_act_kernel<<<dim3(Nh / TBM, H / TBN), 256, 0, stream>>>(
      h1, W2, b2, h2, Nh, H, H, 1);

  // ---- branch 2: res = interp(l_y1 - interp(l_y2; l_pos2->l_pos1); l_pos1->h_pos1) ----
  knn_wave_kernel<<<Nl / 4, 256, 0, stream>>>(
      l_pos1, Nl, G2, offs2, spts2, sidx2,
      1, l_y1, l_y2, nullptr, nullptr, diff);
  knn_wave_kernel<<<Nh / 4, 256, 0, stream>>>(
      h_pos1, Nh, G2, offs3, spts3, sidx3,
      2, nullptr, diff, nullptr, nullptr, res);

  // ---- final: out = (h2 @ W3 + b3) + res ----
  final_kernel<<<Nh / 4, 256, 0, stream>>>(h2, W3, b3, res, out, Nh);
}